// Round 8
// baseline (463.472 us; speedup 1.0000x reference)
//
#include <hip/hip_runtime.h>

// TBStars2 MoE sparse block — fp32 I/O, bf16 MFMA compute
// R16: both cvt kernels deleted.
//  - w1 conversion fused into gemm1's B-staging with a one-K-tile REGISTER
//    prefetch: 8 global_load_dwordx4 (fp32) issued at P0 for tile t+1,
//    cvt8+ds_write into the dead back-buffer at P2 (~2 phases of latency
//    cover), boundary waits vmcnt(0)+lgkmcnt(0). No launch_bounds min-wave
//    cap (R12 spilled at the 128-reg cap; here budget is 256).
//  - w2 conversion free-rides on gemm1's grid: all 2048 blocks (incl. the
//    ~1536 that exit before GEMM work) convert one 8192-elem chunk of w2
//    before the early-exit check — rides under gemm1's 13%-utilized HBM.
//  gemm1 core schedule = R13's reproducible 4-phase form; gemm2/router/
//  scatter = R13 (atomicAdd epilogue, router zeroes out rows, no combine).
#define T 4096
#define Hdim 1024
#define Fdim 2048
#define NE 8
#define TOPK 2
#define TK (T*TOPK)

typedef unsigned short ushort_t;
typedef __attribute__((ext_vector_type(8))) short bf16x8;   // 8 x bf16 (4 VGPRs)
typedef __attribute__((ext_vector_type(4))) float floatx4;  // mfma accumulator

__device__ __forceinline__ ushort_t f2bf(float f) {
    unsigned u = __float_as_uint(f);
    u += 0x7fff + ((u >> 16) & 1);   // RNE
    return (ushort_t)(u >> 16);
}
__device__ __forceinline__ uint4 cvt8(const float4 a, const float4 b) {
    uint4 r;
    r.x = (unsigned)f2bf(a.x) | ((unsigned)f2bf(a.y) << 16);
    r.y = (unsigned)f2bf(a.z) | ((unsigned)f2bf(a.w) << 16);
    r.z = (unsigned)f2bf(b.x) | ((unsigned)f2bf(b.y) << 16);
    r.w = (unsigned)f2bf(b.z) | ((unsigned)f2bf(b.w) << 16);
    return r;
}
// async 16B global->LDS (per-lane gather src; LDS dest = wave base + lane*16)
__device__ __forceinline__ void gld16(const ushort_t* g, short* l) {
    __builtin_amdgcn_global_load_lds((const __attribute__((address_space(1))) void*)g,
                                     (__attribute__((address_space(3))) void*)l, 16, 0, 0);
}

// ---------------------------------------------------------------------------
// K1: router. One wave per token, fp32. Also converts its hs row -> hsb (bf16),
// zeroes its out row (gemm2 accumulates into it atomically), and (block 0)
// zeroes counts.
__global__ __launch_bounds__(64) void router_kernel(
    const float* __restrict__ hs, const float* __restrict__ gw,
    float* __restrict__ logits_out, float* __restrict__ out,
    ushort_t* __restrict__ hsb,
    int2* __restrict__ choice, float2* __restrict__ cwt, int* __restrict__ counts)
{
    const int t = blockIdx.x;
    const int lane = threadIdx.x;
    if (t == 0 && lane < NE) counts[lane] = 0;

    float hreg[16];
#pragma unroll
    for (int i = 0; i < 16; ++i)
        hreg[i] = hs[(long)t * Hdim + lane + 64 * i];

#pragma unroll
    for (int i = 0; i < 16; ++i)
        hsb[(long)t * Hdim + lane + 64 * i] = f2bf(hreg[i]);

    // zero this token's output row (accumulated by gemm2 atomics)
    const float4 z4 = make_float4(0.f, 0.f, 0.f, 0.f);
#pragma unroll
    for (int i = 0; i < 4; ++i)
        *(float4*)&out[(long)t * Hdim + lane * 4 + 256 * i] = z4;

    float acc[NE];
#pragma unroll
    for (int e = 0; e < NE; ++e) {
        float s = 0.f;
#pragma unroll
        for (int i = 0; i < 16; ++i)
            s += hreg[i] * gw[e * Hdim + lane + 64 * i];
#pragma unroll
        for (int off = 32; off > 0; off >>= 1)
            s += __shfl_xor(s, off, 64);
        acc[e] = s;
    }

    if (lane < NE) logits_out[t * NE + lane] = acc[lane];

    if (lane == 0) {
        int i1 = 0;
#pragma unroll
        for (int e = 1; e < NE; ++e) if (acc[e] > acc[i1]) i1 = e;
        int i2 = -1;
#pragma unroll
        for (int e = 0; e < NE; ++e) {
            if (e == i1) continue;
            if (i2 < 0 || acc[e] > acc[i2]) i2 = e;
        }
        float p2 = __expf(acc[i2] - acc[i1]);
        float z  = 1.f + p2;
        choice[t] = make_int2(i1, i2);
        cwt[t]    = make_float2(1.f / z, p2 / z);
    }
}

// K1b: scatter. Block = 256 tokens. LDS histogram -> 8 global atomics/block.
__global__ __launch_bounds__(256) void scatter_kernel(
    const int2* __restrict__ choice, const float2* __restrict__ cwt,
    int* __restrict__ counts, int* __restrict__ tok_slot, float* __restrict__ tok_wt)
{
    __shared__ int lhist[NE];
    __shared__ int lbase[NE];
    __shared__ int lpos[NE];
    const int tid = threadIdx.x;
    if (tid < NE) { lhist[tid] = 0; lpos[tid] = 0; }
    __syncthreads();

    const int t = blockIdx.x * 256 + tid;
    int2   ch = choice[t];
    float2 wv = cwt[t];
    atomicAdd(&lhist[ch.x], 1);
    atomicAdd(&lhist[ch.y], 1);
    __syncthreads();

    if (tid < NE) lbase[tid] = atomicAdd(&counts[tid], lhist[tid]);
    __syncthreads();

    int p1 = atomicAdd(&lpos[ch.x], 1);   // ch.x != ch.y
    int p2 = atomicAdd(&lpos[ch.y], 1);
    int o1 = lbase[ch.x] + p1;
    int o2 = lbase[ch.y] + p2;
    tok_slot[ch.x * T + o1] = t * TOPK + 0;
    tok_wt [ch.x * T + o1] = wv.x;
    tok_slot[ch.y * T + o2] = t * TOPK + 1;
    tok_wt [ch.y * T + o2] = wv.y;
}

// ---------------------------------------------------------------------------
// K2: gather-GEMM1 + SwiGLU + fused w1 cvt + w2 free-ride cvt.
// 256 slots x 128 f (B rows: 128 gate + 128 up), 512 threads = 8 waves
// (4m x 2fn), BK=64, 16 K-tiles, double-buffered LDS (128 KB), R13 4-phase
// schedule. A staged via gld16 from hsb (bf16). B: fp32 w1 loaded to regs at
// P0 (tile t+1), cvt8+ds_write into dead back-buffer at P2.
__global__ __launch_bounds__(512) void gemm1_kernel(
    const ushort_t* __restrict__ hsb, const float* __restrict__ w1,
    const float* __restrict__ w2, ushort_t* __restrict__ w2b,
    const int* __restrict__ counts, const int* __restrict__ tok_slot,
    ushort_t* __restrict__ actb)
{
    const int tid = threadIdx.x;

    // ---- w2 fp32->bf16 free-ride: every block converts its 8192-elem chunk
    // (grid 16x16x8 = 2048 chunks x 8192 = 16.78M = |w2|). Runs before the
    // early-exit so idle blocks contribute; rides under gemm1's spare HBM BW.
    {
        int lin = ((int)blockIdx.z * 16 + (int)blockIdx.y) * 16 + (int)blockIdx.x;
        long base = (long)lin * 8192 + (long)tid * 16;
        float4 x0 = *(const float4*)(w2 + base);
        float4 x1 = *(const float4*)(w2 + base + 4);
        float4 x2 = *(const float4*)(w2 + base + 8);
        float4 x3 = *(const float4*)(w2 + base + 12);
        *(uint4*)(w2b + base)     = cvt8(x0, x1);
        *(uint4*)(w2b + base + 8) = cvt8(x2, x3);
    }

    const int e = blockIdx.z;
    const int cnt = counts[e];
    const int row0 = blockIdx.y * 256;
    if (row0 >= cnt) return;
    const int f0 = blockIdx.x * 128;

    __shared__ short As[2][256 * 64];    // 2 x 32 KB
    __shared__ short Bs[2][256 * 64];    // 2 x 32 KB: rows 0-127 gate, 128-255 up
    __shared__ int slotLds[256];

    if (tid < 256) {
        int idx = row0 + tid;
        slotLds[tid] = (idx < cnt) ? tok_slot[e * T + idx] : -1;
    }
    __syncthreads();

    // A staging: 4 chunks/thread (2048 chunks, gld16, swizzled LDS layout)
    const ushort_t* srcA[4];
    // B staging: 4 chunks/thread, fp32 source, reg-prefetched one tile ahead
    const float* srcBf[4];
    int bDst[4];
#pragma unroll
    for (int i = 0; i < 4; ++i) {
        int ci = i * 512 + tid;            // 0..2047
        int r  = ci >> 3;                  // LDS row 0..255
        int gc = (ci & 7) ^ (r & 7);       // swizzled global chunk
        int s  = slotLds[r];
        srcA[i] = hsb + (long)(s >= 0 ? (s >> 1) : 0) * Hdim + gc * 8;
        long frow = (r < 128) ? (long)(f0 + r) : (long)(Fdim + f0 + (r - 128));
        srcBf[i] = w1 + ((long)e * 2 * Fdim + frow) * Hdim + gc * 8;
        bDst[i]  = ci * 8;
    }

    const int lane = tid & 63;
    const int w = tid >> 6;              // 0..7
    const int wm = (w >> 1) * 64;        // slot-row base: 0/64/128/192
    const int fn = (w & 1) * 64;         // f-col base within 128: 0/64
    const int fr = lane & 15, fg = lane >> 4;
    const int cs0 = (fg ^ (fr & 7)) * 8;          // kk=0 chunk byte-swz (elems)
    const int cs1 = ((4 + fg) ^ (fr & 7)) * 8;    // kk=1

    floatx4 accg[4][4] = {};
    floatx4 accu[4][4] = {};

    // prologue: stage tile 0 (A async, B sync reg->cvt->LDS), full drain
#pragma unroll
    for (int i = 0; i < 4; ++i)
        gld16(srcA[i], &As[0][(i * 512 + tid) * 8]);
    {
        float4 p[8];
#pragma unroll
        for (int i = 0; i < 4; ++i) {
            p[2 * i]     = *(const float4*)(srcBf[i]);
            p[2 * i + 1] = *(const float4*)(srcBf[i] + 4);
        }
#pragma unroll
        for (int i = 0; i < 4; ++i)
            *(uint4*)&Bs[0][bDst[i]] = cvt8(p[2 * i], p[2 * i + 1]);
    }
    __syncthreads();

    float4 br[8];                         // B(t+1) fp32 prefetch registers
    const int NT = Hdim / 64;             // 16 K-tiles
    for (int t = 0; t < NT; ++t) {
        const short* Ac = As[t & 1];
        const short* Bc = Bs[t & 1];
        short* An = As[(t & 1) ^ 1];
        short* Bn = Bs[(t & 1) ^ 1];
        const bool pf = (t + 1 < NT);
        const long k1 = (long)(t + 1) * 64;

        bf16x8 a[4], b[4];

        // ---- phase 0: kk=0, gate; stage A(t+1) async; issue B(t+1) fp32 ----
#pragma unroll
        for (int ms = 0; ms < 4; ++ms)
            a[ms] = *(const bf16x8*)&Ac[(wm + ms * 16 + fr) * 64 + cs0];
#pragma unroll
        for (int ns = 0; ns < 4; ++ns)
            b[ns] = *(const bf16x8*)&Bc[(fn + ns * 16 + fr) * 64 + cs0];
        if (pf) {
#pragma unroll
            for (int i = 0; i < 4; ++i)
                gld16(srcA[i] + k1, &An[(i * 512 + tid) * 8]);
#pragma unroll
            for (int i = 0; i < 4; ++i) {
                br[2 * i]     = *(const float4*)(srcBf[i] + k1);
                br[2 * i + 1] = *(const float4*)(srcBf[i] + k1 + 4);
            }
        }
        __builtin_amdgcn_s_barrier();
        __builtin_amdgcn_s_setprio(1);
#pragma unroll
        for (int ms = 0; ms < 4; ++ms)
#pragma unroll
            for (int ns = 0; ns < 4; ++ns)
                accg[ms][ns] = __builtin_amdgcn_mfma_f32_16x16x32_bf16(a[ms], b[ns], accg[ms][ns], 0, 0, 0);
        __builtin_amdgcn_s_setprio(0);
        __builtin_amdgcn_s_barrier();

        // ---- phase 1: kk=0, up (reuses a) ---------------------------------
#pragma unroll
        for (int ns = 0; ns < 4; ++ns)
            b[ns] = *(const bf16x8*)&Bc[(128 + fn + ns * 16 + fr) * 64 + cs0];
        __builtin_amdgcn_s_barrier();
        __builtin_amdgcn_s_setprio(1);
#pragma unroll
        for (int ms = 0; ms < 4; ++ms)
#pragma unroll
            for (int ns = 0; ns < 4; ++ns)
                accu[ms][ns] = __builtin_amdgcn_mfma_f32_16x16x32_bf16(a[ms], b[ns], accu[ms][ns], 0, 0, 0);
        __builtin_amdgcn_s_setprio(0);
        __builtin_amdgcn_s_barrier();

        // ---- phase 2: kk=1, gate; write B(t+1) into dead back-buffer -------
        // (Bn is dead: its last reads finished before the previous boundary
        //  barrier. Compiler auto-waits the br load deps before cvt8.)
        if (pf) {
#pragma unroll
            for (int i = 0; i < 4; ++i)
                *(uint4*)&Bn[bDst[i]] = cvt8(br[2 * i], br[2 * i + 1]);
        }
#pragma unroll
        for (int ms = 0; ms < 4; ++ms)
            a[ms] = *(const bf16x8*)&Ac[(wm + ms * 16 + fr) * 64 + cs1];
#pragma unroll
        for (int ns = 0; ns < 4; ++ns)
            b[ns] = *(const bf16x8*)&Bc[(fn + ns * 16 + fr) * 64 + cs1];
        __builtin_amdgcn_s_barrier();
        __builtin_amdgcn_s_setprio(1);
#pragma unroll
        for (int ms = 0; ms < 4; ++ms)
#pragma unroll
            for (int ns = 0; ns < 4; ++ns)
                accg[ms][ns] = __builtin_amdgcn_mfma_f32_16x16x32_bf16(a[ms], b[ns], accg[ms][ns], 0, 0, 0);
        __builtin_amdgcn_s_setprio(0);
        __builtin_amdgcn_s_barrier();

        // ---- phase 3: kk=1, up; boundary drain (A gld16 + B ds_writes) -----
#pragma unroll
        for (int ns = 0; ns < 4; ++ns)
            b[ns] = *(const bf16x8*)&Bc[(128 + fn + ns * 16 + fr) * 64 + cs1];
        __builtin_amdgcn_s_barrier();
        __builtin_amdgcn_s_setprio(1);
#pragma unroll
        for (int ms = 0; ms < 4; ++ms)
#pragma unroll
            for (int ns = 0; ns < 4; ++ns)
                accu[ms][ns] = __builtin_amdgcn_mfma_f32_16x16x32_bf16(a[ms], b[ns], accu[ms][ns], 0, 0, 0);
        __builtin_amdgcn_s_setprio(0);
        __builtin_amdgcn_sched_barrier(0);
        asm volatile("s_waitcnt vmcnt(0) lgkmcnt(0)" ::: "memory");
        __builtin_amdgcn_s_barrier();
    }

#pragma unroll
    for (int ms = 0; ms < 4; ++ms)
#pragma unroll
        for (int ns = 0; ns < 4; ++ns)
#pragma unroll
            for (int j = 0; j < 4; ++j) {
                int m = wm + ms * 16 + fg * 4 + j;
                int slot = slotLds[m];
                if (slot >= 0) {
                    int fcol = f0 + fn + ns * 16 + fr;
                    float gv = accg[ms][ns][j];
                    float uv = accu[ms][ns][j];
                    float av = (gv / (1.f + __expf(-gv))) * uv;
                    actb[(long)slot * Fdim + fcol] = f2bf(av);
                }
            }
}

// ---------------------------------------------------------------------------
// K3: gather-GEMM2, 128x128 tile, 512 threads (8 waves, 2x4), BK=64, 32 steps
// (R13 form). Epilogue: atomicAdd wt*y directly into out[token, h].
__global__ __launch_bounds__(512) void gemm2_kernel(
    const ushort_t* __restrict__ actb, const ushort_t* __restrict__ w2b,
    const int* __restrict__ counts, const int* __restrict__ tok_slot,
    const float* __restrict__ tok_wt, float* __restrict__ out)
{
    const int e = blockIdx.z;
    const int cnt = counts[e];
    const int row0 = blockIdx.y * 128;
    if (row0 >= cnt) return;
    const int h0 = blockIdx.x * 128;

    __shared__ short As[128 * 64];
    __shared__ short Bs[128 * 64];
    __shared__ int   slotLds[128];
    __shared__ float wtLds[128];

    const int tid = threadIdx.x;
    if (tid < 128) {
        int idx = row0 + tid;
        bool ok = idx < cnt;
        slotLds[tid] = ok ? tok_slot[e * T + idx] : -1;
        wtLds[tid]   = ok ? tok_wt [e * T + idx] : 0.f;
    }
    __syncthreads();

    const ushort_t* srcA[2];
    const ushort_t* srcB[2];
#pragma unroll
    for (int i = 0; i < 2; ++i) {
        int ci = i * 512 + tid;            // 0..1023
        int r  = ci >> 3;
        int gc = (ci & 7) ^ (r & 7);
        int s  = slotLds[r];
        srcA[i] = actb + (long)(s >= 0 ? s : 0) * Fdim + gc * 8;
        srcB[i] = w2b + ((long)e * Hdim + (h0 + r)) * Fdim + gc * 8;
    }

    const int lane = tid & 63;
    const int w = tid >> 6;              // 0..7
    const int wm = (w >> 2) * 64;
    const int wn = (w & 3) * 32;
    const int fr = lane & 15, fg = lane >> 4;
    const int cs0 = (fg ^ (fr & 7)) * 8;
    const int cs1 = ((4 + fg) ^ (fr & 7)) * 8;

    floatx4 acc[4][2] = {};

    for (int k0 = 0; k0 < Fdim; k0 += 64) {
        __syncthreads();
        gld16(srcA[0] + k0, &As[tid * 8]);
        gld16(srcA[1] + k0, &As[(512 + tid) * 8]);
        gld16(srcB[0] + k0, &Bs[tid * 8]);
        gld16(srcB[1] + k0, &Bs[(512 + tid) * 8]);
        __syncthreads();

#pragma unroll
        for (int kk = 0; kk < 2; ++kk) {
            const int cs = kk ? cs1 : cs0;
            bf16x8 a[4], b[2];
#pragma unroll
            for (int ms = 0; ms < 4; ++ms)
                a[ms] = *(bf16x8*)&As[(wm + ms * 16 + fr) * 64 + cs];
#pragma unroll
            for (int ns = 0; ns < 2; ++ns)
                b[ns] = *(bf16x8*)&Bs[(wn + ns * 16 + fr) * 64 + cs];
#pragma unroll
            for (int ms = 0; ms < 4; ++ms)
#pragma unroll
                for (int ns = 0; ns < 2; ++ns)
                    acc[ms][ns] = __builtin_amdgcn_mfma_f32_16x16x32_bf16(a[ms], b[ns], acc[ms][ns], 0, 0, 0);
        }
    }

#pragma unroll
    for (int ms = 0; ms < 4; ++ms)
#pragma unroll
        for (int ns = 0; ns < 2; ++ns)
#pragma unroll
            for (int j = 0; j < 4; ++j) {
                int m = wm + ms * 16 + fg * 4 + j;
                int slot = slotLds[m];
                if (slot >= 0) {
                    int hcol = h0 + wn + ns * 16 + fr;
                    atomicAdd(&out[(long)(slot >> 1) * Hdim + hcol],
                              acc[ms][ns][j] * wtLds[m]);
                }
            }
}

// ---------------------------------------------------------------------------
extern "C" void kernel_launch(void* const* d_in, const int* in_sizes, int n_in,
                              void* d_out, int out_size, void* d_ws, size_t ws_size,
                              hipStream_t stream)
{
    const float* hs = (const float*)d_in[0];   // [T, H] fp32
    const float* gw = (const float*)d_in[1];   // [E, H] fp32
    const float* w1 = (const float*)d_in[2];   // [E, 2F, H] fp32
    const float* w2 = (const float*)d_in[3];   // [E, H, F] fp32

    float* out        = (float*)d_out;          // [T*H] final hidden (fp32)
    float* logits_out = out + (long)T * Hdim;   // [T*E] router logits (fp32)

    // workspace (~72.3 MB): no w1b (gemm1 reads w1 fp32 directly), w2b filled
    // by gemm1's free-ride conversion. choice/cwt alias actb's head.
    char* ws = (char*)d_ws;
    size_t off = 0;
    int* counts = (int*)(ws + off);          off += 256;
    int* tok_slot = (int*)(ws + off);        off += (size_t)NE * T * sizeof(int);
    float* tok_wt = (float*)(ws + off);      off += (size_t)NE * T * sizeof(float);
    off = (off + 255) & ~(size_t)255;
    ushort_t* hsb = (ushort_t*)(ws + off);   off += (size_t)T * Hdim * sizeof(ushort_t);   // 8 MB
    off = (off + 255) & ~(size_t)255;
    ushort_t* w2b = (ushort_t*)(ws + off);   off += (size_t)NE * Hdim * Fdim * sizeof(ushort_t); // 32 MB
    off = (off + 255) & ~(size_t)255;
    ushort_t* actb = (ushort_t*)(ws + off);  off += (size_t)TK * Fdim * sizeof(ushort_t);  // 32 MB
    int2*   choice = (int2*)actb;                       // 32 KB  (dead before gemm1)
    float2* cwt    = (float2*)((char*)actb + (size_t)T * sizeof(int2));   // 32 KB

    router_kernel<<<T, 64, 0, stream>>>(hs, gw, logits_out, out, hsb, choice, cwt, counts);
    scatter_kernel<<<T / 256, 256, 0, stream>>>(choice, cwt, counts, tok_slot, tok_wt);
    gemm1_kernel<<<dim3(Fdim / 128, T / 256, NE), 512, 0, stream>>>(hsb, w1, w2, w2b, counts, tok_slot, actb);
    gemm2_kernel<<<dim3(Hdim / 128, T / 128, NE), 512, 0, stream>>>(actb, w2b, counts, tok_slot, tok_wt, out);
}